// Round 3
// baseline (451.672 us; speedup 1.0000x reference)
//
#include <hip/hip_runtime.h>
#include <cstdint>
#include <cstddef>

#define CH 128   // channels
#define NB 4     // batch

typedef __attribute__((ext_vector_type(8))) short bf16x8;  // 8 bf16 = 4 VGPRs
typedef __attribute__((ext_vector_type(4))) float f32x4;   // MFMA accumulator

// 3-bit XOR swizzle of the 16B-chunk index within a 128B LDS row, keyed on c.
__device__ __forceinline__ int sigma(int c) { return (c ^ (c >> 3)) & 7; }

__device__ __forceinline__ unsigned short f2bf(float f) {
  union { float f; unsigned u; } v; v.f = f;
  unsigned u = v.u + 0x7FFF + ((v.u >> 16) & 1);   // round-nearest-even
  return (unsigned short)(u >> 16);
}
__device__ __forceinline__ unsigned packbf(float lo, float hi) {
  return ((unsigned)f2bf(hi) << 16) | f2bf(lo);
}

// ---------------------------------------------------------------------------
// Kernel 1: per-batch channel Gram G[b] = A^T A via bf16 MFMA (16x16x32).
// 256 thr = 4 waves, each wave owns a 64x64 output quadrant (4x4 frags).
// 64-row super-steps: stage 64n x 128c bf16 in LDS (c-major rows of 128B,
// XOR-swizzled 16B chunks), two 32-row MFMA passes (kk=0,1), 32 MFMAs/wave.
// A- and B-fragments use the SAME loader => any per-lane k-map cancels in
// A^T A; only the C/D layout (HW-verified m89) must be exact.
// Partial Grams reduced into global f32 gram via atomicAdd (gram pre-zeroed).
// ---------------------------------------------------------------------------
__global__ __launch_bounds__(256, 2) void cam_gram(
    const float* __restrict__ x, float* __restrict__ gram,
    const int N, const int rpc) {
  const int b = blockIdx.y;
  const float* __restrict__ A = x + (size_t)b * N * CH;
  float* __restrict__ G = gram + b * CH * CH;
  const int n0 = blockIdx.x * rpc;
  const int nEnd = (n0 + rpc < N) ? (n0 + rpc) : N;

  __shared__ unsigned short tile[CH][64];   // 16 KB; row c = 128 B = 64 bf16

  const int t    = threadIdx.x;
  const int lane = t & 63;
  const int wave = t >> 6;
  const int wc = (wave >> 1) * 64;          // Gram row-quadrant base (c)
  const int wd = (wave & 1) * 64;           // Gram col-quadrant base (d)
  const int m = lane & 15;                  // fragment row/col within 16
  const int g = lane >> 4;                  // k-group 0..3

  // staging map: thread covers channels sc..sc+3, rows {2sa,2sa+1,+16,+32,...}
  const int sc = (t & 31) * 4;
  const int sa = t >> 5;                    // 0..7

  f32x4 acc[4][4];
#pragma unroll
  for (int i = 0; i < 4; ++i)
#pragma unroll
    for (int j = 0; j < 4; ++j) acc[i][j] = 0.f;

  auto ldrow = [&](int na) -> float4 {
    if (na < nEnd) return *(const float4*)(A + (size_t)na * CH + sc);
    return make_float4(0.f, 0.f, 0.f, 0.f);
  };
  // row offsets of the 8 loads within a 64-row super-step (ushort pair u):
  //   u = sa, sa+8, sa+16, sa+24  <->  n pairs (2u, 2u+1)
  auto ldstep = [&](int nb, float4* cur) {
#pragma unroll
    for (int r = 0; r < 4; ++r) {
      cur[2 * r]     = ldrow(nb + 16 * r + 2 * sa);
      cur[2 * r + 1] = ldrow(nb + 16 * r + 2 * sa + 1);
    }
  };

  float4 cur[8];
  ldstep(n0, cur);

  for (int nb = n0; nb < nEnd; nb += 64) {
    // pack to bf16 pairs along n (vmcnt wait for cur lands here, covered by
    // the previous iteration's MFMA phase)
    unsigned pk[4][4];                      // [r pair][j channel]
#pragma unroll
    for (int r = 0; r < 4; ++r) {
      const float* lo = (const float*)&cur[2 * r];
      const float* hi = (const float*)&cur[2 * r + 1];
#pragma unroll
      for (int j = 0; j < 4; ++j) pk[r][j] = packbf(lo[j], hi[j]);
    }

    __syncthreads();                        // prev super-step's frag reads done
#pragma unroll
    for (int j = 0; j < 4; ++j) {
      const int c = sc + j;
      const int sg = sigma(c);
      char* rowp = (char*)&tile[c][0];
#pragma unroll
      for (int r = 0; r < 4; ++r) {
        const int o = 4 * sa + 32 * r;      // unswizzled byte offset in row
        *(unsigned*)(rowp + ((((o >> 4) ^ sg) << 4) | (o & 15))) = pk[r][j];
      }
    }
    __syncthreads();                        // tile visible

    // issue next super-step's loads now: in flight across frag reads + MFMAs
    if (nb + 64 < nEnd) ldstep(nb + 64, cur);

    const char* tb = (const char*)&tile[0][0];
#pragma unroll
    for (int kk = 0; kk < 2; ++kk) {        // two 32-row MFMA passes
      bf16x8 af[4], bfr[4];
#pragma unroll
      for (int i = 0; i < 4; ++i) {
        const int c = wc + i * 16 + m;
        af[i] = *(const bf16x8*)(tb + c * 128 + (((kk * 4 + g) ^ sigma(c)) << 4));
      }
#pragma unroll
      for (int j = 0; j < 4; ++j) {
        const int d = wd + j * 16 + m;
        bfr[j] = *(const bf16x8*)(tb + d * 128 + (((kk * 4 + g) ^ sigma(d)) << 4));
      }
#pragma unroll
      for (int i = 0; i < 4; ++i)
#pragma unroll
        for (int j = 0; j < 4; ++j)
          acc[i][j] = __builtin_amdgcn_mfma_f32_16x16x32_bf16(af[i], bfr[j],
                                                              acc[i][j], 0, 0, 0);
    }
  }

  // epilogue: C/D layout (HW-verified m89): col = lane&15, row = (lane>>4)*4+reg
#pragma unroll
  for (int i = 0; i < 4; ++i) {
    const int r0 = wc + i * 16 + g * 4;
#pragma unroll
    for (int j = 0; j < 4; ++j) {
      const int cb = wd + j * 16 + m;
#pragma unroll
      for (int r = 0; r < 4; ++r)
        atomicAdd(&G[(size_t)(r0 + r) * CH + cb], acc[i][j][r]);
    }
  }
}

// ---------------------------------------------------------------------------
// Kernel 2: row softmax of gram (in place) + per-batch identity detection.
// One wave per row. viol[b] stays 0 iff softmax is bit-exactly one-hot on the
// diagonal for every row of batch b.
// ---------------------------------------------------------------------------
__global__ __launch_bounds__(256) void cam_softmax(
    float* __restrict__ gram, int* __restrict__ viol) {
  const int row  = blockIdx.x * 4 + (threadIdx.x >> 6);  // 0..NB*CH-1
  const int b    = row >> 7;
  const int r    = row & (CH - 1);
  const int lane = threadIdx.x & 63;
  float* __restrict__ G = gram + (size_t)b * CH * CH + (size_t)r * CH;

  float v0 = G[lane], v1 = G[lane + 64];
  float mx = fmaxf(v0, v1);
#pragma unroll
  for (int o = 32; o; o >>= 1) mx = fmaxf(mx, __shfl_xor(mx, o));
  const float e0 = expf(v0 - mx), e1 = expf(v1 - mx);
  float s = e0 + e1;
#pragma unroll
  for (int o = 32; o; o >>= 1) s += __shfl_xor(s, o);
  const float s0 = e0 / s, s1 = e1 / s;
  G[lane]      = s0;
  G[lane + 64] = s1;

  const bool ok = (s0 == ((lane == r) ? 1.f : 0.f)) &&
                  (s1 == ((lane + 64 == r) ? 1.f : 0.f));
  const unsigned long long bad = __ballot(!ok);
  if (lane == 0 && bad) atomicOr(&viol[b], 1);
}

// ---------------------------------------------------------------------------
// Kernel 3: output. Identity fast path: out = gamma*x + x, float4 streaming
// (x is L3-resident after the gram pass; writes are the HBM cost).
// General fallback (never taken for this input distribution): full A @ s.
// ---------------------------------------------------------------------------
__global__ __launch_bounds__(256) void cam_out(
    const float* __restrict__ x, const float* __restrict__ sm,
    const int* __restrict__ viol, const float* __restrict__ gamma,
    float* __restrict__ out, const int N) {
  const int b = blockIdx.y;
  const float gm = *gamma;
  const size_t base = (size_t)b * N * CH;

  if (viol[b] == 0) {
    const size_t total4 = ((size_t)N * CH) >> 2;
    const float4* __restrict__ xi = (const float4*)(x + base);
    float4* __restrict__ oo = (float4*)(out + base);
    const size_t stride = (size_t)gridDim.x * blockDim.x;
#pragma unroll 4
    for (size_t i = (size_t)blockIdx.x * blockDim.x + threadIdx.x;
         i < total4; i += stride) {
      float4 v = xi[i];
      float4 r;
      r.x = gm * v.x + v.x;
      r.y = gm * v.y + v.y;
      r.z = gm * v.z + v.z;
      r.w = gm * v.w + v.w;
      oo[i] = r;
    }
  } else {
    const float* __restrict__ S = sm + (size_t)b * CH * CH;
    const size_t total = (size_t)N * CH;
    const size_t stride = (size_t)gridDim.x * blockDim.x;
    for (size_t e = (size_t)blockIdx.x * blockDim.x + threadIdx.x;
         e < total; e += stride) {
      const size_t n = e >> 7;
      const int d = (int)(e & (CH - 1));
      const float* __restrict__ arow = x + base + n * CH;
      float a = 0.f;
#pragma unroll 4
      for (int c = 0; c < CH; ++c) a = fmaf(arow[c], S[(size_t)c * CH + d], a);
      out[base + e] = gm * a + x[base + e];
    }
  }
}

// ---------------------------------------------------------------------------
extern "C" void kernel_launch(void* const* d_in, const int* in_sizes, int n_in,
                              void* d_out, int out_size, void* d_ws, size_t ws_size,
                              hipStream_t stream) {
  const float* x     = (const float*)d_in[0];
  const float* gamma = (const float*)d_in[1];
  float* out = (float*)d_out;

  const int N = in_sizes[0] / (NB * CH);            // 110592 for 48^3

  float* gram = (float*)d_ws;                       // NB*CH*CH f32 = 256 KB
  int* viol = (int*)((char*)d_ws + (size_t)NB * CH * CH * sizeof(float));

  hipMemsetAsync(d_ws, 0,
                 (size_t)NB * CH * CH * sizeof(float) + NB * sizeof(int),
                 stream);

  const int rpc = 576;                              // 9 super-steps of 64 rows
  const int chunks = (N + rpc - 1) / rpc;           // 192 for N=110592
  cam_gram<<<dim3(chunks, NB), 256, 0, stream>>>(x, gram, N, rpc);

  cam_softmax<<<dim3(NB * CH / 4), 256, 0, stream>>>(gram, viol);

  cam_out<<<dim3(1024, NB), 256, 0, stream>>>(x, gram, viol, gamma, out, N);
}